// Round 12
// baseline (2033.510 us; speedup 1.0000x reference)
//
#include <hip/hip_runtime.h>

#define B_ 512
#define L_ 1000
#define H_ 128
#define G_ 512  // 4*H

typedef _Float16 v8h __attribute__((ext_vector_type(8)));
typedef _Float16 h4t __attribute__((ext_vector_type(4)));
typedef float v4f __attribute__((ext_vector_type(4)));

__device__ __forceinline__ float sigmoid_f(float x) {
  return __builtin_amdgcn_rcpf(1.0f + __builtin_amdgcn_exp2f(-1.4426950408889634f * x));
}
__device__ __forceinline__ float tanh_f(float x) {
  return 1.0f - 2.0f * __builtin_amdgcn_rcpf(1.0f + __builtin_amdgcn_exp2f(2.8853900817779268f * x));
}

// h storage in B-FRAGMENT ORDER: chunk (kt, quad', row) at byte offset
// kt*144 + quad'*32 + row*16 holds h_row[kt*32 + quad'*8 + jj], jj=0..7 (f16).
// C-read (per kt): quad*32 + (m15&1)*16 -> 8 distinct addrs, one per
// bank-group -> pure broadcast, zero conflicts. U-write: one b64/active lane,
// 8 distinct addrs -> <=2-way = free (m136).
#define FB_KT 144

#define MFMA16(a, b, c) __builtin_amdgcn_mfma_f32_16x16x32_f16((a), (b), (c), 0, 0, 0)

// ROUND-11 (= ROUND-10 FUSED-8 resubmit after third audit; infra fail).
// r9 A/B locked the model: per-C-burst overhead scales with wave count;
// U-hiding via burst-splitting is a net loss (r6: +2000cy, r9: +300cy).
// LEAN-8 = 3850cy/step: 1920 MFMA + ~1930 overhead (serial SegU + gbuf
// round-trip + 2 barriers). FUSED-8 removes the gbuf round-trip AND the
// serial U-segment by mtile re-assignment: wave w owns mtiles
// {w, 8+w, 16+w, 24+w} = the i/f/g/o quadruple for h-elements 16w..16w+15.
// After its MFMAs, lane (quad, m15<2) reg j holds i,f,g,o for element
// e=16w+4q+j, row m15, IN REGISTERS -> LSTM cell update fully in-lane
// (c-state in-lane too); only the packed f16 h-fragment (b64) touches LDS.
// Biases fold into MFMA acc-init (C-in = bbb LDS read). Per step t:
//   Seg1: A1@h1(t-1) (16 MFMA/wave) + U1(t) in-reg -> hb1[t&1]   | barrier
//   Seg2: A2i@h1(t)+A2h@h2(t-1) (32 MFMA/wave) + U2(t) in-reg ->
//         hb2[t&1], out(t) = shfl-reduce + 2 LDS atomicAdd        | barrier
// Deps: hb1[t&1]: Seg1(t)->Seg2(t) (1 bar) & Seg1(t+1) writes other parity;
// hb2[t&1]: Seg2(t)->Seg2(t+1) (2 bars), read parity != write parity.
// t=0 reads parity-1 buffers (zeroed) = h1(-1)=h2(-1)=0. Loop t=0..L-1.
__global__ __launch_bounds__(512, 2) void lstm_mfma(
    const float* __restrict__ x,
    const float* __restrict__ w_ih1,
    const float* __restrict__ w_hh1,
    const float* __restrict__ b_ih1,
    const float* __restrict__ b_hh1,
    const float* __restrict__ w_ih2,
    const float* __restrict__ w_hh2,
    const float* __restrict__ b_ih2,
    const float* __restrict__ b_hh2,
    const float* __restrict__ w_lin,
    const float* __restrict__ b_lin,
    float* __restrict__ out)
{
  __shared__ __align__(16) float xlds[2][L_];        // block's 2 x-rows
  __shared__ __align__(16) float olds[2 * L_];       // out accum (atomics)
  __shared__ __align__(16) unsigned char hb1[2][4 * FB_KT];  // [parity] h1
  __shared__ __align__(16) unsigned char hb2[2][4 * FB_KT];  // [parity] h2
  __shared__ __align__(16) float wxb[G_];            // w_ih1 column
  __shared__ __align__(16) float bbb1[G_];           // b_ih1+b_hh1
  __shared__ __align__(16) float bbb2[G_];           // b_ih2+b_hh2
  __shared__ __align__(16) float wlb[H_];            // w_lin row

  const int tid  = threadIdx.x;        // 0..511
  const int wv   = tid >> 6;           // 0..7
  const int lane = tid & 63;
  const int quad = lane >> 4;
  const int m15  = lane & 15;
  const int r0   = blockIdx.x * 2;

  // ---- one-time staging / zero-init ----
  for (int i = tid; i < 2 * L_; i += 512) {
    ((float*)xlds)[i] = x[r0 * L_ + i];
    olds[i] = 0.f;
  }
  wxb[tid]  = w_ih1[tid];              // tid spans exactly G_
  bbb1[tid] = b_ih1[tid] + b_hh1[tid];
  bbb2[tid] = b_ih2[tid] + b_hh2[tid];
  if (tid < H_) wlb[tid] = w_lin[tid];
  if (tid < 288) {                      // 2*4*FB_KT/4 dwords each buffer
    ((unsigned*)hb1)[tid] = 0u;         // h1(-1)=0 (both parities)
    ((unsigned*)hb2)[tid] = 0u;         // h2(-1)=0
  }
  const float blv = b_lin[0];

  // ---- per-wave fragments: mtiles {wv, 8+wv, 16+wv, 24+wv} (i,f,g,o) ----
  v8h A1f[4][4], A2if[4][4], A2hf[4][4];
#pragma unroll
  for (int m = 0; m < 4; ++m) {
    const int grow = ((wv + 8 * m) * 16 + m15) * H_;
#pragma unroll
    for (int kt = 0; kt < 4; ++kt) {
      const int koff = kt * 32 + quad * 8;
      float4 a, b;
      a = *(const float4*)(w_hh1 + grow + koff);
      b = *(const float4*)(w_hh1 + grow + koff + 4);
      A1f[m][kt] = v8h{(_Float16)a.x, (_Float16)a.y, (_Float16)a.z, (_Float16)a.w,
                       (_Float16)b.x, (_Float16)b.y, (_Float16)b.z, (_Float16)b.w};
      a = *(const float4*)(w_ih2 + grow + koff);
      b = *(const float4*)(w_ih2 + grow + koff + 4);
      A2if[m][kt] = v8h{(_Float16)a.x, (_Float16)a.y, (_Float16)a.z, (_Float16)a.w,
                        (_Float16)b.x, (_Float16)b.y, (_Float16)b.z, (_Float16)b.w};
      a = *(const float4*)(w_hh2 + grow + koff);
      b = *(const float4*)(w_hh2 + grow + koff + 4);
      A2hf[m][kt] = v8h{(_Float16)a.x, (_Float16)a.y, (_Float16)a.z, (_Float16)a.w,
                        (_Float16)b.x, (_Float16)b.y, (_Float16)b.z, (_Float16)b.w};
    }
  }

  // in-lane cell state for elements e = 16*wv + 4*quad + j (rows = m15<2)
  float c10 = 0.f, c11 = 0.f, c12 = 0.f, c13 = 0.f;
  float c20 = 0.f, c21 = 0.f, c22 = 0.f, c23 = 0.f;

  const int cbase = 16 * wv + 4 * quad;            // element/gate sub-index
  const int roff  = quad * 32 + (m15 & 1) * 16;    // B-frag read offset
  // h-pack write: 4 f16 at byte (wv>>1)*144 + quad'*32 + row*16 + (quad&1)*8
  const int hwo2 = (wv >> 1) * FB_KT + ((16 * (wv & 1) + 4 * quad) >> 3) * 32
                 + (m15 & 1) * 16 + (quad & 1) * 8;

  __syncthreads();

  for (int t = 0; t < L_; ++t) {
    // ===== Seg1: a = b1-init + A1@h1(t-1); U1(t) in-reg -> hb1[t&1] =====
    v4f a0 = *(const v4f*)&bbb1[cbase];
    v4f a1 = *(const v4f*)&bbb1[128 + cbase];
    v4f a2 = *(const v4f*)&bbb1[256 + cbase];
    v4f a3 = *(const v4f*)&bbb1[384 + cbase];
    {
      const unsigned char* bp = &hb1[(t + 1) & 1][0];  // h1(t-1)
      __builtin_amdgcn_s_setprio(1);
#pragma unroll
      for (int kt = 0; kt < 4; ++kt) {
        v8h b = *(const v8h*)(bp + kt * FB_KT + roff);
        a0 = MFMA16(A1f[0][kt], b, a0);
        a1 = MFMA16(A1f[1][kt], b, a1);
        a2 = MFMA16(A1f[2][kt], b, a2);
        a3 = MFMA16(A1f[3][kt], b, a3);
      }
      __builtin_amdgcn_s_setprio(0);
    }
    {
      const float xv = xlds[m15 & 1][t];
      v4f wxi = *(const v4f*)&wxb[cbase];
      v4f wxf = *(const v4f*)&wxb[128 + cbase];
      v4f wxg = *(const v4f*)&wxb[256 + cbase];
      v4f wxo = *(const v4f*)&wxb[384 + cbase];
      float h0, h1, h2, h3;
      { float iv = sigmoid_f(a0[0] + wxi[0] * xv), fv = sigmoid_f(a1[0] + wxf[0] * xv);
        float gv = tanh_f(a2[0] + wxg[0] * xv),    ov = sigmoid_f(a3[0] + wxo[0] * xv);
        c10 = fv * c10 + iv * gv; h0 = ov * tanh_f(c10); }
      { float iv = sigmoid_f(a0[1] + wxi[1] * xv), fv = sigmoid_f(a1[1] + wxf[1] * xv);
        float gv = tanh_f(a2[1] + wxg[1] * xv),    ov = sigmoid_f(a3[1] + wxo[1] * xv);
        c11 = fv * c11 + iv * gv; h1 = ov * tanh_f(c11); }
      { float iv = sigmoid_f(a0[2] + wxi[2] * xv), fv = sigmoid_f(a1[2] + wxf[2] * xv);
        float gv = tanh_f(a2[2] + wxg[2] * xv),    ov = sigmoid_f(a3[2] + wxo[2] * xv);
        c12 = fv * c12 + iv * gv; h2 = ov * tanh_f(c12); }
      { float iv = sigmoid_f(a0[3] + wxi[3] * xv), fv = sigmoid_f(a1[3] + wxf[3] * xv);
        float gv = tanh_f(a2[3] + wxg[3] * xv),    ov = sigmoid_f(a3[3] + wxo[3] * xv);
        c13 = fv * c13 + iv * gv; h3 = ov * tanh_f(c13); }
      h4t hp = h4t{(_Float16)h0, (_Float16)h1, (_Float16)h2, (_Float16)h3};
      if (m15 < 2) *(h4t*)(&hb1[t & 1][0] + hwo2) = hp;
    }
    __syncthreads();

    // ===== Seg2: d = b2-init + A2i@h1(t) + A2h@h2(t-1); U2(t); out(t) =====
    v4f d0 = *(const v4f*)&bbb2[cbase];
    v4f d1 = *(const v4f*)&bbb2[128 + cbase];
    v4f d2 = *(const v4f*)&bbb2[256 + cbase];
    v4f d3 = *(const v4f*)&bbb2[384 + cbase];
    {
      const unsigned char* p1 = &hb1[t & 1][0];        // h1(t)
      const unsigned char* p2 = &hb2[(t + 1) & 1][0];  // h2(t-1)
      __builtin_amdgcn_s_setprio(1);
#pragma unroll
      for (int kt = 0; kt < 4; ++kt) {
        v8h b1 = *(const v8h*)(p1 + kt * FB_KT + roff);
        v8h b2 = *(const v8h*)(p2 + kt * FB_KT + roff);
        d0 = MFMA16(A2if[0][kt], b1, d0);
        d1 = MFMA16(A2if[1][kt], b1, d1);
        d2 = MFMA16(A2if[2][kt], b1, d2);
        d3 = MFMA16(A2if[3][kt], b1, d3);
        d0 = MFMA16(A2hf[0][kt], b2, d0);
        d1 = MFMA16(A2hf[1][kt], b2, d1);
        d2 = MFMA16(A2hf[2][kt], b2, d2);
        d3 = MFMA16(A2hf[3][kt], b2, d3);
      }
      __builtin_amdgcn_s_setprio(0);
    }
    {
      float h0, h1, h2, h3;
      { float iv = sigmoid_f(d0[0]), fv = sigmoid_f(d1[0]);
        float gv = tanh_f(d2[0]),    ov = sigmoid_f(d3[0]);
        c20 = fv * c20 + iv * gv; h0 = ov * tanh_f(c20); }
      { float iv = sigmoid_f(d0[1]), fv = sigmoid_f(d1[1]);
        float gv = tanh_f(d2[1]),    ov = sigmoid_f(d3[1]);
        c21 = fv * c21 + iv * gv; h1 = ov * tanh_f(c21); }
      { float iv = sigmoid_f(d0[2]), fv = sigmoid_f(d1[2]);
        float gv = tanh_f(d2[2]),    ov = sigmoid_f(d3[2]);
        c22 = fv * c22 + iv * gv; h2 = ov * tanh_f(c22); }
      { float iv = sigmoid_f(d0[3]), fv = sigmoid_f(d1[3]);
        float gv = tanh_f(d2[3]),    ov = sigmoid_f(d3[3]);
        c23 = fv * c23 + iv * gv; h3 = ov * tanh_f(c23); }
      h4t hp = h4t{(_Float16)h0, (_Float16)h1, (_Float16)h2, (_Float16)h3};
      if (m15 < 2) *(h4t*)(&hb2[t & 1][0] + hwo2) = hp;
      v4f wlv = *(const v4f*)&wlb[cbase];
      float p = h0 * wlv[0] + h1 * wlv[1] + h2 * wlv[2] + h3 * wlv[3];
      p += __shfl_xor(p, 16, 64);   // sum over quads (m15 preserved)
      p += __shfl_xor(p, 32, 64);
      if (lane < 2) atomicAdd(&olds[lane * L_ + t], p);  // 8 waves accumulate
    }
    __syncthreads();
  }

  // ---- one-shot coalesced flush (add output bias once) ----
  for (int i = tid; i < 2 * L_; i += 512) out[r0 * L_ + i] = olds[i] + blv;
}

extern "C" void kernel_launch(void* const* d_in, const int* in_sizes, int n_in,
                              void* d_out, int out_size, void* d_ws, size_t ws_size,
                              hipStream_t stream) {
  const float* x     = (const float*)d_in[0];
  const float* w_ih1 = (const float*)d_in[1];
  const float* w_hh1 = (const float*)d_in[2];
  const float* b_ih1 = (const float*)d_in[3];
  const float* b_hh1 = (const float*)d_in[4];
  const float* w_ih2 = (const float*)d_in[5];
  const float* w_hh2 = (const float*)d_in[6];
  const float* b_ih2 = (const float*)d_in[7];
  const float* b_hh2 = (const float*)d_in[8];
  const float* w_lin = (const float*)d_in[9];
  const float* b_lin = (const float*)d_in[10];

  lstm_mfma<<<B_ / 2, 512, 0, stream>>>(
      x, w_ih1, w_hh1, b_ih1, b_hh1, w_ih2, w_hh2, b_ih2, b_hh2,
      w_lin, b_lin, (float*)d_out);
}

// Round 13
// 1414.165 us; speedup vs baseline: 1.4380x; 1.4380x over previous
//
#include <hip/hip_runtime.h>

#define B_ 512
#define L_ 1000
#define H_ 128
#define G_ 512  // 4*H

typedef _Float16 v8h __attribute__((ext_vector_type(8)));
typedef float v4f __attribute__((ext_vector_type(4)));

__device__ __forceinline__ float sigmoid_f(float x) {
  return __builtin_amdgcn_rcpf(1.0f + __builtin_amdgcn_exp2f(-1.4426950408889634f * x));
}
__device__ __forceinline__ float tanh_f(float x) {
  return 1.0f - 2.0f * __builtin_amdgcn_rcpf(1.0f + __builtin_amdgcn_exp2f(2.8853900817779268f * x));
}
// constant-index extract tree: 3 v_cndmask, no scratch (rule #20 safe)
__device__ __forceinline__ float sel4(v4f v, int j) {
  float lo = (j & 1) ? v[1] : v[0];
  float hi = (j & 1) ? v[3] : v[2];
  return (j & 2) ? hi : lo;
}

// h storage in B-FRAGMENT ORDER: chunk (kt, quad', row) at byte offset
// kt*144 + quad'*32 + row*16 holds h_row[kt*32 + quad'*8 + jj], jj=0..7 (f16).
// C-read (per kt): quad*32 + (m15&1)*16 -> 8 distinct addrs, one per
// bank-group -> pure broadcast, zero conflicts (verified r10: conflicts=0).
#define FB_KT 144

#define MFMA16(a, b, c) __builtin_amdgcn_mfma_f32_16x16x32_f16((a), (b), (c), 0, 0, 0)

// ROUND-12: FUSED-8-SPLIT. r10 post-mortem: FUSED-8 zeroed bank conflicts
// but VALUBusy hit 57% -- every lane updated 4 elements x 2 layers (8x the
// needed per-SIMD VALU inst load; duplicate MFMA columns recompute the same
// update). Fix: the duplicate columns ARE the resource -- lanes (m15=2k,
// 2k+1) hold gate regs identical to lanes (0,1), so column-pair k owns
// element j=k: each lane updates ONE element (3-cndmask selection from its
// 4 regs), keeps 1 c-value, writes 1 f16. 256 updates/segment/block = zero
// redundancy; per-wave U cost drops 4x. w_ih1/w_lin become per-lane scalar
// preloads (wxb/wlb deleted). Out: shfl_xor{2,4,16,32} + 2 LDS atomics.
// Schedule per step t (2 barriers, same as r10):
//   Seg1: a = bbb1 + A1@h1(t-1) (16 MFMA/wave); U1(t) 1-elem -> hb1[t&1]
//   Seg2: d = bbb2 + A2i@h1(t) + A2h@h2(t-1) (32 MFMA/wave); U2(t) 1-elem
//         -> hb2[t&1]; out(t) partial reduce + atomicAdd
// Deps: hb1[t&1]: Seg1(t)->Seg2(t) (1 bar); Seg1(t+1) writes other parity.
// hb2: read (t+1)&1 / write t&1 -> crosses 2 bars. t=0 reads zeroed parity-1.
__global__ __launch_bounds__(512, 2) void lstm_mfma(
    const float* __restrict__ x,
    const float* __restrict__ w_ih1,
    const float* __restrict__ w_hh1,
    const float* __restrict__ b_ih1,
    const float* __restrict__ b_hh1,
    const float* __restrict__ w_ih2,
    const float* __restrict__ w_hh2,
    const float* __restrict__ b_ih2,
    const float* __restrict__ b_hh2,
    const float* __restrict__ w_lin,
    const float* __restrict__ b_lin,
    float* __restrict__ out)
{
  __shared__ __align__(16) float xlds[2][L_];        // block's 2 x-rows
  __shared__ __align__(16) float olds[2 * L_];       // out accum (atomics)
  __shared__ __align__(16) unsigned char hb1[2][4 * FB_KT];  // [parity] h1
  __shared__ __align__(16) unsigned char hb2[2][4 * FB_KT];  // [parity] h2
  __shared__ __align__(16) float bbb1[G_];           // b_ih1+b_hh1 (MFMA C-in)
  __shared__ __align__(16) float bbb2[G_];           // b_ih2+b_hh2

  const int tid  = threadIdx.x;        // 0..511
  const int wv   = tid >> 6;           // 0..7
  const int lane = tid & 63;
  const int quad = lane >> 4;
  const int m15  = lane & 15;
  const int r0   = blockIdx.x * 2;

  // ---- one-time staging / zero-init ----
  for (int i = tid; i < 2 * L_; i += 512) {
    ((float*)xlds)[i] = x[r0 * L_ + i];
    olds[i] = 0.f;
  }
  bbb1[tid] = b_ih1[tid] + b_hh1[tid];   // tid spans exactly G_
  bbb2[tid] = b_ih2[tid] + b_hh2[tid];
  if (tid < 288) {                        // 2*4*FB_KT/4 dwords each buffer
    ((unsigned*)hb1)[tid] = 0u;           // h1(-1)=0 (both parities)
    ((unsigned*)hb2)[tid] = 0u;           // h2(-1)=0
  }
  const float blv = b_lin[0];

  // ---- per-lane element assignment: column-pair (2k,2k+1) owns j=k ----
  const int jsel = (m15 >> 1) & 3;                 // m15>=8 aliases j=0 (masked)
  const int rsel = m15 & 1;                        // batch row
  const int esel = 16 * wv + 4 * quad + jsel;      // owned h-element
  const float wxi_s = w_ih1[esel];
  const float wxf_s = w_ih1[128 + esel];
  const float wxg_s = w_ih1[256 + esel];
  const float wxo_s = w_ih1[384 + esel];
  const float wl_s  = w_lin[esel];
  // 1-element f16 write offset for (esel, rsel)
  const int hwo1 = (wv >> 1) * FB_KT + (2 * (wv & 1) + (quad >> 1)) * 32
                 + rsel * 16 + (4 * (quad & 1) + jsel) * 2;

  // ---- per-wave fragments: mtiles {wv, 8+wv, 16+wv, 24+wv} (i,f,g,o) ----
  v8h A1f[4][4], A2if[4][4], A2hf[4][4];
#pragma unroll
  for (int m = 0; m < 4; ++m) {
    const int grow = ((wv + 8 * m) * 16 + m15) * H_;
#pragma unroll
    for (int kt = 0; kt < 4; ++kt) {
      const int koff = kt * 32 + quad * 8;
      float4 a, b;
      a = *(const float4*)(w_hh1 + grow + koff);
      b = *(const float4*)(w_hh1 + grow + koff + 4);
      A1f[m][kt] = v8h{(_Float16)a.x, (_Float16)a.y, (_Float16)a.z, (_Float16)a.w,
                       (_Float16)b.x, (_Float16)b.y, (_Float16)b.z, (_Float16)b.w};
      a = *(const float4*)(w_ih2 + grow + koff);
      b = *(const float4*)(w_ih2 + grow + koff + 4);
      A2if[m][kt] = v8h{(_Float16)a.x, (_Float16)a.y, (_Float16)a.z, (_Float16)a.w,
                        (_Float16)b.x, (_Float16)b.y, (_Float16)b.z, (_Float16)b.w};
      a = *(const float4*)(w_hh2 + grow + koff);
      b = *(const float4*)(w_hh2 + grow + koff + 4);
      A2hf[m][kt] = v8h{(_Float16)a.x, (_Float16)a.y, (_Float16)a.z, (_Float16)a.w,
                        (_Float16)b.x, (_Float16)b.y, (_Float16)b.z, (_Float16)b.w};
    }
  }

  float c1 = 0.f, c2 = 0.f;  // in-lane cell state for element (esel, rsel)

  const int cbase = 16 * wv + 4 * quad;            // MFMA acc-init index
  const int roff  = quad * 32 + (m15 & 1) * 16;    // B-frag read offset

  __syncthreads();

  for (int t = 0; t < L_; ++t) {
    // ===== Seg1: a = bbb1 + A1@h1(t-1); U1(t) 1-elem -> hb1[t&1] =====
    v4f a0 = *(const v4f*)&bbb1[cbase];
    v4f a1 = *(const v4f*)&bbb1[128 + cbase];
    v4f a2 = *(const v4f*)&bbb1[256 + cbase];
    v4f a3 = *(const v4f*)&bbb1[384 + cbase];
    {
      const unsigned char* bp = &hb1[(t + 1) & 1][0];  // h1(t-1)
      __builtin_amdgcn_s_setprio(1);
#pragma unroll
      for (int kt = 0; kt < 4; ++kt) {
        v8h b = *(const v8h*)(bp + kt * FB_KT + roff);
        a0 = MFMA16(A1f[0][kt], b, a0);
        a1 = MFMA16(A1f[1][kt], b, a1);
        a2 = MFMA16(A1f[2][kt], b, a2);
        a3 = MFMA16(A1f[3][kt], b, a3);
      }
      __builtin_amdgcn_s_setprio(0);
    }
    {
      const float xv = xlds[rsel][t];
      float iv = sigmoid_f(sel4(a0, jsel) + wxi_s * xv);
      float fv = sigmoid_f(sel4(a1, jsel) + wxf_s * xv);
      float gv = tanh_f(sel4(a2, jsel) + wxg_s * xv);
      float ov = sigmoid_f(sel4(a3, jsel) + wxo_s * xv);
      c1 = fv * c1 + iv * gv;
      float h = ov * tanh_f(c1);
      if (m15 < 8) *(_Float16*)(&hb1[t & 1][0] + hwo1) = (_Float16)h;
    }
    __syncthreads();

    // ===== Seg2: d = bbb2 + A2i@h1(t) + A2h@h2(t-1); U2(t); out(t) =====
    v4f d0 = *(const v4f*)&bbb2[cbase];
    v4f d1 = *(const v4f*)&bbb2[128 + cbase];
    v4f d2 = *(const v4f*)&bbb2[256 + cbase];
    v4f d3 = *(const v4f*)&bbb2[384 + cbase];
    {
      const unsigned char* p1 = &hb1[t & 1][0];        // h1(t)
      const unsigned char* p2 = &hb2[(t + 1) & 1][0];  // h2(t-1)
      __builtin_amdgcn_s_setprio(1);
#pragma unroll
      for (int kt = 0; kt < 4; ++kt) {
        v8h b1 = *(const v8h*)(p1 + kt * FB_KT + roff);
        v8h b2 = *(const v8h*)(p2 + kt * FB_KT + roff);
        d0 = MFMA16(A2if[0][kt], b1, d0);
        d1 = MFMA16(A2if[1][kt], b1, d1);
        d2 = MFMA16(A2if[2][kt], b1, d2);
        d3 = MFMA16(A2if[3][kt], b1, d3);
        d0 = MFMA16(A2hf[0][kt], b2, d0);
        d1 = MFMA16(A2hf[1][kt], b2, d1);
        d2 = MFMA16(A2hf[2][kt], b2, d2);
        d3 = MFMA16(A2hf[3][kt], b2, d3);
      }
      __builtin_amdgcn_s_setprio(0);
    }
    {
      float iv = sigmoid_f(sel4(d0, jsel));
      float fv = sigmoid_f(sel4(d1, jsel));
      float gv = tanh_f(sel4(d2, jsel));
      float ov = sigmoid_f(sel4(d3, jsel));
      c2 = fv * c2 + iv * gv;
      float h = ov * tanh_f(c2);
      if (m15 < 8) *(_Float16*)(&hb2[t & 1][0] + hwo1) = (_Float16)h;
      float p = (m15 < 8) ? h * wl_s : 0.f;  // m15>=8 alias j=0: mask out
      p += __shfl_xor(p, 2, 64);    // sum over j-pairs (bit1)
      p += __shfl_xor(p, 4, 64);    // (bit2)
      p += __shfl_xor(p, 16, 64);   // quads
      p += __shfl_xor(p, 32, 64);
      if (lane < 2) atomicAdd(&olds[lane * L_ + t], p);  // lane0=row0, lane1=row1
    }
    __syncthreads();
  }

  // ---- one-shot coalesced flush (add output bias once) ----
  for (int i = tid; i < 2 * L_; i += 512) out[r0 * L_ + i] = olds[i] + blv;
}

extern "C" void kernel_launch(void* const* d_in, const int* in_sizes, int n_in,
                              void* d_out, int out_size, void* d_ws, size_t ws_size,
                              hipStream_t stream) {
  const float* x     = (const float*)d_in[0];
  const float* w_ih1 = (const float*)d_in[1];
  const float* w_hh1 = (const float*)d_in[2];
  const float* b_ih1 = (const float*)d_in[3];
  const float* b_hh1 = (const float*)d_in[4];
  const float* w_ih2 = (const float*)d_in[5];
  const float* w_hh2 = (const float*)d_in[6];
  const float* b_ih2 = (const float*)d_in[7];
  const float* b_hh2 = (const float*)d_in[8];
  const float* w_lin = (const float*)d_in[9];
  const float* b_lin = (const float*)d_in[10];

  lstm_mfma<<<B_ / 2, 512, 0, stream>>>(
      x, w_ih1, w_hh1, b_ih1, b_hh1, w_ih2, w_hh2, b_ih2, b_hh2,
      w_lin, b_lin, (float*)d_out);
}